// Round 5
// baseline (148.180 us; speedup 1.0000x reference)
//
#include <hip/hip_runtime.h>
#include <type_traits>

typedef short bf16x8 __attribute__((ext_vector_type(8)));
typedef float f32x4 __attribute__((ext_vector_type(4)));

// ---------------- problem constants ----------------
constexpr int Hh = 14, Ww = 14, Cc = 512, Bb = 512, NR = 70, PadR = 80;

// ---------------- constexpr replication of _crop_boxes ----------------
struct Box { int y1, y2, x1, x2; };

constexpr double cfloor(double v) { return (double)(long long)v; }  // v >= 0 only
constexpr double cround(double v) {  // np.round: half-to-even
    double f = cfloor(v);
    double fr = v - f;
    if (fr > 0.5) return f + 1.0;
    if (fr < 0.5) return f;
    return (((long long)f) & 1LL) ? f + 1.0 : f;
}

struct BoxArr { Box b[NR]; };

constexpr BoxArr make_boxes() {
    BoxArr out{};
    double rx_[14] = {}, ry_[14] = {}, wl_[14] = {};
    int nr = 0;
    for (int l = 1; l <= 3; ++l) {
        double wl  = cfloor(2.0 * 14.0 / (double)(l + 1));
        double wl2 = cfloor(wl / 2.0 - 1.0);
        double bb  = (l > 1) ? (14.0 - wl) / (double)(l - 1) : 0.0;
        double cen[3] = {};
        for (int k = 0; k < l; ++k) cen[k] = cfloor(wl2 + (double)k * bb) - wl2;
        for (int i = 0; i < l; ++i)
            for (int j = 0; j < l; ++j) { rx_[nr] = cen[j]; ry_[nr] = cen[i]; wl_[nr] = wl; ++nr; }
    }
    int nb = 0;
    for (int r = 0; r < nr; ++r) {
        for (int p = 1; p <= 2; ++p) {
            double len = wl_[r] / (double)p;
            for (int ix = 0; ix < p; ++ix)
                for (int jy = 0; jy < p; ++jy) {
                    int x1 = (int)cround(rx_[r] + ix * len);
                    int x2 = (int)cround(rx_[r] + ix * len + len);
                    int y1 = (int)cround(ry_[r] + jy * len);
                    int y2 = (int)cround(ry_[r] + jy * len + len);
                    out.b[nb] = Box{y1, y2, x1, x2};
                    ++nb;
                }
        }
    }
    return out;
}
constexpr BoxArr BOXES = make_boxes();

// distinct x-interval dedup
struct Meta { int nxi; int xlo[32]; int xhi[32]; int xid[NR]; };
constexpr Meta make_meta() {
    Meta m{};
    m.nxi = 0;
    for (int r = 0; r < NR; ++r) {
        int lo = BOXES.b[r].x1, hi = BOXES.b[r].x2, id = -1;
        for (int i = 0; i < m.nxi; ++i) if (m.xlo[i] == lo && m.xhi[i] == hi) { id = i; break; }
        if (id < 0) { id = m.nxi; m.xlo[id] = lo; m.xhi[id] = hi; m.nxi++; }
        m.xid[r] = id;
    }
    return m;
}
constexpr Meta MT = make_meta();
constexpr int NXI = MT.nxi;
static_assert(NXI == 14, "expected 14 distinct x-intervals");

// per-h box lists (boxes whose [y1,y2) contains h) -- for streaming row RMW
struct HRows { int cnt[Hh]; int idx[Hh][40]; };
constexpr HRows make_hb() {
    HRows hb{};
    for (int h = 0; h < Hh; ++h) {
        hb.cnt[h] = 0;
        for (int r = 0; r < NR; ++r)
            if (BOXES.b[r].y1 <= h && h < BOXES.b[r].y2) {
                hb.idx[h][hb.cnt[h]] = r;
                hb.cnt[h]++;
            }
    }
    return hb;
}
constexpr HRows HB = make_hb();
constexpr int hb_max() { int m = 0; for (int h = 0; h < Hh; ++h) m = HB.cnt[h] > m ? HB.cnt[h] : m; return m; }
static_assert(hb_max() <= 40, "HB idx array too small");

__device__ __forceinline__ ushort f2bf(float f) {  // RNE float->bf16 (finite; -inf ok)
    union { float f; unsigned u; } v; v.f = f;
    unsigned r = v.u + 0x7FFFu + ((v.u >> 16) & 1u);
    return (ushort)(r >> 16);
}
__device__ __forceinline__ float bf2f(ushort u) {
    union { unsigned u; float f; } v; v.u = ((unsigned)u) << 16;
    return v.f;
}

// swizzled index into m_s[80][512]: 16B slots XOR'd by row&7 (matches GEMM read)
__device__ __forceinline__ int midx(int r, int c) {
    return r * Cc + (((c >> 3) ^ (r & 7)) << 3) + (c & 7);
}

// ---------------- kernel 0: W fp32 -> bf16 ----------------
__global__ __launch_bounds__(256) void k_convw(const float* __restrict__ w,
                                               ushort* __restrict__ o) {
    int i = (blockIdx.x * 256 + threadIdx.x) * 4;
    float4 f = *(const float4*)&w[i];
    ushort4 u;
    u.x = f2bf(f.x); u.y = f2bf(f.y); u.z = f2bf(f.z); u.w = f2bf(f.w);
    *(ushort4*)&o[i] = u;
}

// ---------------- fused: streaming-row pool (contiguous x reads) -> GEMM ---------
// 7 steps x 2 rows: load 56KB of x FULLY CONTIGUOUSLY into LDS, then each thread
// owns one channel and RMW-maxes m_s[box][c] for boxes containing each row.
// bf16 max is monotone => iterated bf(max(bf(m), rowmax)) == bf(max over rows):
// bit-exact with the old two-phase fold. GEMM + epilogue identical to round 0.
__global__ __launch_bounds__(512) void k_fused(const float* __restrict__ x,
                                               const ushort* __restrict__ wbf,
                                               const float* __restrict__ bias,
                                               float* __restrict__ out) {
    __shared__ __align__(16) ushort m_s[PadR * Cc];          // 80 KB, XOR-swizzled
    __shared__ __align__(16) union UU {
        float xraw[2 * Ww * Cc];                             // 56 KB (2 image rows)
        struct {                                             // epilogue scratch (aliased)
            float rowss[PadR][8];
            float rns[PadR];
            float y_s[Cc];
            float red2[8];
        } e;
    } u;
    __shared__ float ss_s[PadR];
    __shared__ float rnm[PadR];

    const int b = blockIdx.x;
    const int tid = threadIdx.x;
    const int lane = tid & 63;
    const int wv = tid >> 6;                // 0..7
    const int l15 = lane & 15, lhi = lane >> 4;

    // init m_s: rows 0..69 -> -inf bf16 (0xFF80), pad rows 70..79 -> 0
    {
        uint* z = (uint*)m_s;
        #pragma unroll
        for (int i = 0; i < 40; ++i)
            z[tid + i * 512] = (i < 35) ? 0xFF80FF80u : 0u;   // 35*512 uints = rows 0..69
        if (tid >= 70 && tid < PadR) ss_s[tid] = 0.f;
    }

    const float* xb = x + (size_t)b * (Hh * Ww * Cc);
    float4 stg[7];                           // staged 2-row chunk (contiguous)
    auto loadStep = [&](int s) {
        const float4* xs = (const float4*)(xb + s * (2 * Ww * Cc));
        #pragma unroll
        for (int k = 0; k < 7; ++k) stg[k] = xs[tid + k * 512];
    };
    auto writeStage = [&]() {
        #pragma unroll
        for (int k = 0; k < 7; ++k)
            *(float4*)&u.xraw[(size_t)(tid + k * 512) * 4] = stg[k];
    };
    auto foldStep = [&](auto SC) {           // fold rows h=2S, 2S+1 (compile-time)
        constexpr int S = SC.value;
        #pragma unroll
        for (int hh = 0; hh < 2; ++hh) {
            float row[Ww];
            #pragma unroll
            for (int w = 0; w < Ww; ++w) row[w] = u.xraw[hh * (Ww * Cc) + w * Cc + tid];
            float rmx[NXI];
            #pragma unroll
            for (int xi = 0; xi < NXI; ++xi) {
                float mm = row[MT.xlo[xi]];
                #pragma unroll
                for (int w = MT.xlo[xi] + 1; w < MT.xhi[xi]; ++w) mm = fmaxf(mm, row[w]);
                rmx[xi] = mm;
            }
            #pragma unroll
            for (int bi = 0; bi < HB.cnt[S * 2 + hh]; ++bi) {
                const int r = HB.idx[S * 2 + hh][bi];
                const int a = midx(r, tid);
                m_s[a] = f2bf(fmaxf(bf2f(m_s[a]), rmx[MT.xid[r]]));
            }
        }
    };
    auto stepRun = [&](auto SC) {
        constexpr int S = SC.value;
        writeStage();                        // vmcnt(0) then LDS write
        __syncthreads();                     // xraw ready (and m_s init on S=0)
        if constexpr (S < 6) loadStep(S + 1);// next chunk streams under fold
        foldStep(SC);
        __syncthreads();                     // fold done before next writeStage
    };

    loadStep(0);
    stepRun(std::integral_constant<int, 0>{});
    stepRun(std::integral_constant<int, 1>{});
    stepRun(std::integral_constant<int, 2>{});
    stepRun(std::integral_constant<int, 3>{});
    stepRun(std::integral_constant<int, 4>{});
    stepRun(std::integral_constant<int, 5>{});
    stepRun(std::integral_constant<int, 6>{});

    // ---- SS from m_s, replicating old per-lane/per-cg accumulation order ----
    #pragma unroll
    for (int i = 0; i < 9; ++i) {
        const int rr = wv * 9 + i;
        if (rr < NR) {
            float s = 0.f;
            #pragma unroll
            for (int cg = 0; cg < 4; ++cg) {
                ushort2 t2 = *(const ushort2*)&m_s[midx(rr, cg * 128 + 2 * lane)];
                float m0 = bf2f(t2.x), m1 = bf2f(t2.y);
                s += m0 * m0 + m1 * m1;
            }
            s += __shfl_xor(s, 1);  s += __shfl_xor(s, 2);  s += __shfl_xor(s, 4);
            s += __shfl_xor(s, 8);  s += __shfl_xor(s, 16); s += __shfl_xor(s, 32);
            if (lane == 0) ss_s[rr] = s;
        }
    }
    __syncthreads();
    if (tid < PadR) rnm[tid] = 1.f / fmaxf(sqrtf(ss_s[tid]), 1e-12f);
    __syncthreads();

    // ---- GEMM: t[80][512] = m * W^T, A resident in m_s, no barriers ----
    f32x4 acc[5][4];
    #pragma unroll
    for (int mi = 0; mi < 5; ++mi)
        #pragma unroll
        for (int ni = 0; ni < 4; ++ni) acc[mi][ni] = (f32x4){0.f, 0.f, 0.f, 0.f};

    auto loadB = [&](bf16x8 (&bf)[4][2], int k0) {
        #pragma unroll
        for (int ni = 0; ni < 4; ++ni)
            #pragma unroll
            for (int kh = 0; kh < 2; ++kh)
                bf[ni][kh] = *(const bf16x8*)(wbf + (size_t)(wv * 64 + ni * 16 + l15) * Cc
                                              + k0 + kh * 32 + lhi * 8);
    };

    bf16x8 bfc[4][2], bfn[4][2];
    loadB(bfc, 0);
    #pragma unroll
    for (int ks = 0; ks < 8; ++ks) {
        if (ks < 7) loadB(bfn, (ks + 1) * 64);
        #pragma unroll
        for (int kh = 0; kh < 2; ++kh) {
            bf16x8 af[5];
            #pragma unroll
            for (int mi = 0; mi < 5; ++mi) {
                int row_ = mi * 16 + l15;
                int slot = (ks * 8 + kh * 4 + lhi) ^ (row_ & 7);
                af[mi] = *(const bf16x8*)&m_s[row_ * Cc + slot * 8];
            }
            #pragma unroll
            for (int mi = 0; mi < 5; ++mi)
                #pragma unroll
                for (int ni = 0; ni < 4; ++ni)
                    acc[mi][ni] = __builtin_amdgcn_mfma_f32_16x16x32_bf16(
                        af[mi], bfc[ni][kh], acc[mi][ni], 0, 0, 0);
        }
        #pragma unroll
        for (int ni = 0; ni < 4; ++ni)
            #pragma unroll
            for (int kh = 0; kh < 2; ++kh) bfc[ni][kh] = bfn[ni][kh];
    }
    __syncthreads();                          // m_s/xraw reads done; epilogue may alias

    // ---- fused epilogue: deferred A-norm + bias, row-norm, sum, final norm ----
    float bia[4];
    #pragma unroll
    for (int ni = 0; ni < 4; ++ni) bia[ni] = bias[wv * 64 + ni * 16 + l15];
    float rm[5][4];
    #pragma unroll
    for (int mi = 0; mi < 5; ++mi)
        #pragma unroll
        for (int j = 0; j < 4; ++j) rm[mi][j] = rnm[mi * 16 + lhi * 4 + j];
    #pragma unroll
    for (int mi = 0; mi < 5; ++mi)
        #pragma unroll
        for (int ni = 0; ni < 4; ++ni)
            #pragma unroll
            for (int j = 0; j < 4; ++j)
                acc[mi][ni][j] = fmaf(acc[mi][ni][j], rm[mi][j], bia[ni]);

    #pragma unroll
    for (int mi = 0; mi < 5; ++mi)
        #pragma unroll
        for (int j = 0; j < 4; ++j) {
            float s = 0.f;
            #pragma unroll
            for (int ni = 0; ni < 4; ++ni) s += acc[mi][ni][j] * acc[mi][ni][j];
            s += __shfl_xor(s, 1); s += __shfl_xor(s, 2);
            s += __shfl_xor(s, 4); s += __shfl_xor(s, 8);
            if (l15 == 0) u.e.rowss[mi * 16 + lhi * 4 + j][wv] = s;
        }
    __syncthreads();
    if (tid < PadR) {
        float s = 0.f;
        #pragma unroll
        for (int w8 = 0; w8 < 8; ++w8) s += u.e.rowss[tid][w8];
        u.e.rns[tid] = 1.f / fmaxf(sqrtf(s), 1e-12f);
    }
    __syncthreads();

    float ys[4] = {0.f, 0.f, 0.f, 0.f};
    #pragma unroll
    for (int mi = 0; mi < 5; ++mi)
        #pragma unroll
        for (int j = 0; j < 4; ++j) {
            int row_ = mi * 16 + lhi * 4 + j;
            float w = (row_ < NR) ? u.e.rns[row_] : 0.f;   // skip pad rows
            #pragma unroll
            for (int ni = 0; ni < 4; ++ni) ys[ni] = fmaf(acc[mi][ni][j], w, ys[ni]);
        }
    #pragma unroll
    for (int ni = 0; ni < 4; ++ni) {
        ys[ni] += __shfl_xor(ys[ni], 16);
        ys[ni] += __shfl_xor(ys[ni], 32);
    }
    if (lane < 16)
        #pragma unroll
        for (int ni = 0; ni < 4; ++ni) u.e.y_s[wv * 64 + ni * 16 + lane] = ys[ni];
    __syncthreads();

    float yv = u.e.y_s[tid];
    float s2 = yv * yv;
    s2 += __shfl_xor(s2, 1);  s2 += __shfl_xor(s2, 2);  s2 += __shfl_xor(s2, 4);
    s2 += __shfl_xor(s2, 8);  s2 += __shfl_xor(s2, 16); s2 += __shfl_xor(s2, 32);
    if (lane == 0) u.e.red2[wv] = s2;
    __syncthreads();
    float tot = 0.f;
    #pragma unroll
    for (int w8 = 0; w8 < 8; ++w8) tot += u.e.red2[w8];
    out[(size_t)b * Cc + tid] = yv / fmaxf(sqrtf(tot), 1e-12f);
}

// ---------------- launch ----------------
extern "C" void kernel_launch(void* const* d_in, const int* in_sizes, int n_in,
                              void* d_out, int out_size, void* d_ws, size_t ws_size,
                              hipStream_t stream) {
    const float* x  = (const float*)d_in[0];
    const float* pw = (const float*)d_in[1];
    const float* pb = (const float*)d_in[2];
    float* out = (float*)d_out;

    ushort* wbf = (ushort*)d_ws;                          // 512x512 bf16 = 0.5 MB

    k_convw<<<dim3(256), dim3(256), 0, stream>>>(pw, wbf);
    k_fused<<<dim3(Bb), dim3(512), 0, stream>>>(x, wbf, pb, out);
}

// Round 6
// 88.049 us; speedup vs baseline: 1.6829x; 1.6829x over previous
//
#include <hip/hip_runtime.h>
#include <type_traits>

typedef short bf16x8 __attribute__((ext_vector_type(8)));
typedef float f32x4 __attribute__((ext_vector_type(4)));

// ---------------- problem constants ----------------
constexpr int Hh = 14, Ww = 14, Cc = 512, Bb = 512, NR = 70, PadR = 80;
constexpr int MROWS = 78;   // LDS rows for m: 70 data + 8 zero-pad (78/79 remapped)

// ---------------- constexpr replication of _crop_boxes ----------------
struct Box { int y1, y2, x1, x2; };

constexpr double cfloor(double v) { return (double)(long long)v; }  // v >= 0 only
constexpr double cround(double v) {  // np.round: half-to-even
    double f = cfloor(v);
    double fr = v - f;
    if (fr > 0.5) return f + 1.0;
    if (fr < 0.5) return f;
    return (((long long)f) & 1LL) ? f + 1.0 : f;
}

struct BoxArr { Box b[NR]; };

constexpr BoxArr make_boxes() {
    BoxArr out{};
    double rx_[14] = {}, ry_[14] = {}, wl_[14] = {};
    int nr = 0;
    for (int l = 1; l <= 3; ++l) {
        double wl  = cfloor(2.0 * 14.0 / (double)(l + 1));
        double wl2 = cfloor(wl / 2.0 - 1.0);
        double bb  = (l > 1) ? (14.0 - wl) / (double)(l - 1) : 0.0;
        double cen[3] = {};
        for (int k = 0; k < l; ++k) cen[k] = cfloor(wl2 + (double)k * bb) - wl2;
        for (int i = 0; i < l; ++i)
            for (int j = 0; j < l; ++j) { rx_[nr] = cen[j]; ry_[nr] = cen[i]; wl_[nr] = wl; ++nr; }
    }
    int nb = 0;
    for (int r = 0; r < nr; ++r) {
        for (int p = 1; p <= 2; ++p) {
            double len = wl_[r] / (double)p;
            for (int ix = 0; ix < p; ++ix)
                for (int jy = 0; jy < p; ++jy) {
                    int x1 = (int)cround(rx_[r] + ix * len);
                    int x2 = (int)cround(rx_[r] + ix * len + len);
                    int y1 = (int)cround(ry_[r] + jy * len);
                    int y2 = (int)cround(ry_[r] + jy * len + len);
                    out.b[nb] = Box{y1, y2, x1, x2};
                    ++nb;
                }
        }
    }
    return out;
}
constexpr BoxArr BOXES = make_boxes();

// distinct x-interval dedup
struct Meta { int nxi; int xlo[32]; int xhi[32]; int xid[NR]; };
constexpr Meta make_meta() {
    Meta m{};
    m.nxi = 0;
    for (int r = 0; r < NR; ++r) {
        int lo = BOXES.b[r].x1, hi = BOXES.b[r].x2, id = -1;
        for (int i = 0; i < m.nxi; ++i) if (m.xlo[i] == lo && m.xhi[i] == hi) { id = i; break; }
        if (id < 0) { id = m.nxi; m.xlo[id] = lo; m.xhi[id] = hi; m.nxi++; }
        m.xid[r] = id;
    }
    return m;
}
constexpr Meta MT = make_meta();
constexpr int NXI = MT.nxi;
static_assert(NXI == 14, "expected 14 distinct x-intervals");

// per-h box lists (boxes whose [y1,y2) contains h) -- register y-fold
struct HRows { int cnt[Hh]; int idx[Hh][40]; };
constexpr HRows make_hb() {
    HRows hb{};
    for (int h = 0; h < Hh; ++h) {
        hb.cnt[h] = 0;
        for (int r = 0; r < NR; ++r)
            if (BOXES.b[r].y1 <= h && h < BOXES.b[r].y2) {
                hb.idx[h][hb.cnt[h]] = r;
                hb.cnt[h]++;
            }
    }
    return hb;
}
constexpr HRows HB = make_hb();
constexpr int hb_max() { int m = 0; for (int h = 0; h < Hh; ++h) m = HB.cnt[h] > m ? HB.cnt[h] : m; return m; }
static_assert(hb_max() <= 40, "HB idx array too small");

__device__ __forceinline__ ushort f2bf(float f) {  // RNE float->bf16 (finite; -inf ok)
    union { float f; unsigned u; } v; v.f = f;
    unsigned r = v.u + 0x7FFFu + ((v.u >> 16) & 1u);
    return (ushort)(r >> 16);
}
__device__ __forceinline__ float bf2f(ushort u) {
    union { unsigned u; float f; } v; v.u = ((unsigned)u) << 16;
    return v.f;
}

// swizzled index into m_s[78][512]: 16B slots XOR'd by row&7 (matches GEMM read)
__device__ __forceinline__ int midx(int r, int c) {
    return r * Cc + (((c >> 3) ^ (r & 7)) << 3) + (c & 7);
}

// ---------------- kernel 0: W fp32 -> bf16 ----------------
__global__ __launch_bounds__(256) void k_convw(const float* __restrict__ w,
                                               ushort* __restrict__ o) {
    int i = (blockIdx.x * 256 + threadIdx.x) * 4;
    float4 f = *(const float4*)&w[i];
    ushort4 u;
    u.x = f2bf(f.x); u.y = f2bf(f.y); u.z = f2bf(f.z); u.w = f2bf(f.w);
    *(ushort4*)&o[i] = u;
}

// ---------------- fused: REGISTER pooling (thread = channel) -> GEMM -------------
// Thread tid owns channel c=tid for the whole image: per row h, load 14 floats
// (wave = 256B contiguous per (h,w)), fold 14 x-intervals in regs, update the
// compile-time box list for h in 70 f32 register accumulators. NO LDS / barriers
// in pooling. One handoff write to m_s (bf16, XOR-swizzled), then R0's verified
// MFMA GEMM + fused norm epilogue (scratch aliased into m_s after GEMM).
__global__ __launch_bounds__(512) void k_fused(const float* __restrict__ x,
                                               const ushort* __restrict__ wbf,
                                               const float* __restrict__ bias,
                                               float* __restrict__ out) {
    __shared__ __align__(16) ushort m_s[MROWS * Cc];         // 78 KB, XOR-swizzled
    __shared__ float ss_s[PadR];

    struct EScratch {                                        // 4.96 KB, aliases m_s
        float rowss[PadR][8];
        float rns[PadR];
        float y_s[Cc];
        float red2[8];
    };
    EScratch* sc = (EScratch*)m_s;

    const int b = blockIdx.x;
    const int tid = threadIdx.x;
    const int lane = tid & 63;
    const int wv = tid >> 6;                // 0..7
    const int l15 = lane & 15, lhi = lane >> 4;

    // zero pad rows 70..77 (8 rows x 512 ushort = 2048 uints) and ss_s tail
    {
        uint* z = (uint*)&m_s[70 * Cc];
        #pragma unroll
        for (int i = 0; i < 4; ++i) z[tid + i * 512] = 0;
        if (tid >= 70 && tid < PadR) ss_s[tid] = 0.f;
    }

    // ---- register pooling: 70 f32 accumulators, per-h compile-time box lists ----
    float acc70[NR];
    #pragma unroll
    for (int r = 0; r < NR; ++r) acc70[r] = -INFINITY;

    const float* xc = x + (size_t)b * (Hh * Ww * Cc) + tid;  // channel = tid
    #pragma unroll
    for (int h = 0; h < Hh; ++h) {
        float row[Ww];
        #pragma unroll
        for (int w = 0; w < Ww; ++w) row[w] = xc[(h * Ww + w) * Cc];
        float rmx[NXI];
        #pragma unroll
        for (int xi = 0; xi < NXI; ++xi) {
            float mm = row[MT.xlo[xi]];
            #pragma unroll
            for (int w = MT.xlo[xi] + 1; w < MT.xhi[xi]; ++w) mm = fmaxf(mm, row[w]);
            rmx[xi] = mm;
        }
        #pragma unroll
        for (int bi = 0; bi < HB.cnt[h]; ++bi) {
            const int r = HB.idx[h][bi];
            acc70[r] = fmaxf(acc70[r], rmx[MT.xid[r]]);
        }
    }

    // ---- handoff: quantize once (monotone => bit-identical to fold-of-bf16) ----
    #pragma unroll
    for (int r = 0; r < NR; ++r) m_s[midx(r, tid)] = f2bf(acc70[r]);
    __syncthreads();                         // m_s complete (incl. pad zeros)

    // ---- SS from m_s (same read/accumulate order as previous rounds) ----
    #pragma unroll
    for (int i = 0; i < 9; ++i) {
        const int rr = wv * 9 + i;
        if (rr < NR) {
            float s = 0.f;
            #pragma unroll
            for (int cg = 0; cg < 4; ++cg) {
                ushort2 t2 = *(const ushort2*)&m_s[midx(rr, cg * 128 + 2 * lane)];
                float m0 = bf2f(t2.x), m1 = bf2f(t2.y);
                s += m0 * m0 + m1 * m1;
            }
            s += __shfl_xor(s, 1);  s += __shfl_xor(s, 2);  s += __shfl_xor(s, 4);
            s += __shfl_xor(s, 8);  s += __shfl_xor(s, 16); s += __shfl_xor(s, 32);
            if (lane == 0) ss_s[rr] = s;
        }
    }
    __syncthreads();                         // ss_s ready

    // ---- GEMM: t[80][512] = m * W^T, A resident in m_s, no barriers ----
    f32x4 acc[5][4];
    #pragma unroll
    for (int mi = 0; mi < 5; ++mi)
        #pragma unroll
        for (int ni = 0; ni < 4; ++ni) acc[mi][ni] = (f32x4){0.f, 0.f, 0.f, 0.f};

    auto loadB = [&](bf16x8 (&bf)[4][2], int k0) {
        #pragma unroll
        for (int ni = 0; ni < 4; ++ni)
            #pragma unroll
            for (int kh = 0; kh < 2; ++kh)
                bf[ni][kh] = *(const bf16x8*)(wbf + (size_t)(wv * 64 + ni * 16 + l15) * Cc
                                              + k0 + kh * 32 + lhi * 8);
    };

    bf16x8 bfc[4][2], bfn[4][2];
    loadB(bfc, 0);
    #pragma unroll
    for (int ks = 0; ks < 8; ++ks) {
        if (ks < 7) loadB(bfn, (ks + 1) * 64);
        #pragma unroll
        for (int kh = 0; kh < 2; ++kh) {
            bf16x8 af[5];
            #pragma unroll
            for (int mi = 0; mi < 5; ++mi) {
                int row_ = mi * 16 + l15;
                // rows 78/79 don't exist in LDS: remap to zero rows 70/71
                int rc = (mi < 4) ? row_ : (row_ < MROWS ? row_ : row_ - 8);
                int slot = (ks * 8 + kh * 4 + lhi) ^ (rc & 7);
                af[mi] = *(const bf16x8*)&m_s[rc * Cc + slot * 8];
            }
            #pragma unroll
            for (int mi = 0; mi < 5; ++mi)
                #pragma unroll
                for (int ni = 0; ni < 4; ++ni)
                    acc[mi][ni] = __builtin_amdgcn_mfma_f32_16x16x32_bf16(
                        af[mi], bfc[ni][kh], acc[mi][ni], 0, 0, 0);
        }
        #pragma unroll
        for (int ni = 0; ni < 4; ++ni)
            #pragma unroll
            for (int kh = 0; kh < 2; ++kh) bfc[ni][kh] = bfn[ni][kh];
    }
    __syncthreads();                          // m_s reads done; epilogue may alias

    // ---- fused epilogue: deferred A-norm + bias, row-norm, sum, final norm ----
    float bia[4];
    #pragma unroll
    for (int ni = 0; ni < 4; ++ni) bia[ni] = bias[wv * 64 + ni * 16 + l15];
    float rm[5][4];
    #pragma unroll
    for (int mi = 0; mi < 5; ++mi)
        #pragma unroll
        for (int j = 0; j < 4; ++j)
            rm[mi][j] = 1.f / fmaxf(sqrtf(ss_s[mi * 16 + lhi * 4 + j]), 1e-12f);
    #pragma unroll
    for (int mi = 0; mi < 5; ++mi)
        #pragma unroll
        for (int ni = 0; ni < 4; ++ni)
            #pragma unroll
            for (int j = 0; j < 4; ++j)
                acc[mi][ni][j] = fmaf(acc[mi][ni][j], rm[mi][j], bia[ni]);

    #pragma unroll
    for (int mi = 0; mi < 5; ++mi)
        #pragma unroll
        for (int j = 0; j < 4; ++j) {
            float s = 0.f;
            #pragma unroll
            for (int ni = 0; ni < 4; ++ni) s += acc[mi][ni][j] * acc[mi][ni][j];
            s += __shfl_xor(s, 1); s += __shfl_xor(s, 2);
            s += __shfl_xor(s, 4); s += __shfl_xor(s, 8);
            if (l15 == 0) sc->rowss[mi * 16 + lhi * 4 + j][wv] = s;
        }
    __syncthreads();
    if (tid < PadR) {
        float s = 0.f;
        #pragma unroll
        for (int w8 = 0; w8 < 8; ++w8) s += sc->rowss[tid][w8];
        sc->rns[tid] = 1.f / fmaxf(sqrtf(s), 1e-12f);
    }
    __syncthreads();

    float ys[4] = {0.f, 0.f, 0.f, 0.f};
    #pragma unroll
    for (int mi = 0; mi < 5; ++mi)
        #pragma unroll
        for (int j = 0; j < 4; ++j) {
            int row_ = mi * 16 + lhi * 4 + j;
            float w = (row_ < NR) ? sc->rns[row_] : 0.f;   // skip pad rows
            #pragma unroll
            for (int ni = 0; ni < 4; ++ni) ys[ni] = fmaf(acc[mi][ni][j], w, ys[ni]);
        }
    #pragma unroll
    for (int ni = 0; ni < 4; ++ni) {
        ys[ni] += __shfl_xor(ys[ni], 16);
        ys[ni] += __shfl_xor(ys[ni], 32);
    }
    if (lane < 16)
        #pragma unroll
        for (int ni = 0; ni < 4; ++ni) sc->y_s[wv * 64 + ni * 16 + lane] = ys[ni];
    __syncthreads();

    float yv = sc->y_s[tid];
    float s2 = yv * yv;
    s2 += __shfl_xor(s2, 1);  s2 += __shfl_xor(s2, 2);  s2 += __shfl_xor(s2, 4);
    s2 += __shfl_xor(s2, 8);  s2 += __shfl_xor(s2, 16); s2 += __shfl_xor(s2, 32);
    if (lane == 0) sc->red2[wv] = s2;
    __syncthreads();
    float tot = 0.f;
    #pragma unroll
    for (int w8 = 0; w8 < 8; ++w8) tot += sc->red2[w8];
    out[(size_t)b * Cc + tid] = yv / fmaxf(sqrtf(tot), 1e-12f);
}

// ---------------- launch ----------------
extern "C" void kernel_launch(void* const* d_in, const int* in_sizes, int n_in,
                              void* d_out, int out_size, void* d_ws, size_t ws_size,
                              hipStream_t stream) {
    const float* x  = (const float*)d_in[0];
    const float* pw = (const float*)d_in[1];
    const float* pb = (const float*)d_in[2];
    float* out = (float*)d_out;

    ushort* wbf = (ushort*)d_ws;                          // 512x512 bf16 = 0.5 MB

    k_convw<<<dim3(256), dim3(256), 0, stream>>>(pw, wbf);
    k_fused<<<dim3(Bb), dim3(512), 0, stream>>>(x, wbf, pb, out);
}

// Round 7
// 86.117 us; speedup vs baseline: 1.7207x; 1.0224x over previous
//
#include <hip/hip_runtime.h>
#include <type_traits>

typedef short bf16x8 __attribute__((ext_vector_type(8)));
typedef float f32x4 __attribute__((ext_vector_type(4)));

// ---------------- problem constants ----------------
constexpr int Hh = 14, Ww = 14, Cc = 512, Bb = 512, NR = 70, PadR = 80;
constexpr int MROWS = 72;   // LDS rows for m: 70 data + 2 zero rows (72..79 remapped)

// ---------------- constexpr replication of _crop_boxes ----------------
struct Box { int y1, y2, x1, x2; };

constexpr double cfloor(double v) { return (double)(long long)v; }  // v >= 0 only
constexpr double cround(double v) {  // np.round: half-to-even
    double f = cfloor(v);
    double fr = v - f;
    if (fr > 0.5) return f + 1.0;
    if (fr < 0.5) return f;
    return (((long long)f) & 1LL) ? f + 1.0 : f;
}

struct BoxArr { Box b[NR]; };

constexpr BoxArr make_boxes() {
    BoxArr out{};
    double rx_[14] = {}, ry_[14] = {}, wl_[14] = {};
    int nr = 0;
    for (int l = 1; l <= 3; ++l) {
        double wl  = cfloor(2.0 * 14.0 / (double)(l + 1));
        double wl2 = cfloor(wl / 2.0 - 1.0);
        double bb  = (l > 1) ? (14.0 - wl) / (double)(l - 1) : 0.0;
        double cen[3] = {};
        for (int k = 0; k < l; ++k) cen[k] = cfloor(wl2 + (double)k * bb) - wl2;
        for (int i = 0; i < l; ++i)
            for (int j = 0; j < l; ++j) { rx_[nr] = cen[j]; ry_[nr] = cen[i]; wl_[nr] = wl; ++nr; }
    }
    int nb = 0;
    for (int r = 0; r < nr; ++r) {
        for (int p = 1; p <= 2; ++p) {
            double len = wl_[r] / (double)p;
            for (int ix = 0; ix < p; ++ix)
                for (int jy = 0; jy < p; ++jy) {
                    int x1 = (int)cround(rx_[r] + ix * len);
                    int x2 = (int)cround(rx_[r] + ix * len + len);
                    int y1 = (int)cround(ry_[r] + jy * len);
                    int y2 = (int)cround(ry_[r] + jy * len + len);
                    out.b[nb] = Box{y1, y2, x1, x2};
                    ++nb;
                }
        }
    }
    return out;
}
constexpr BoxArr BOXES = make_boxes();

// distinct x-interval dedup
struct Meta { int nxi; int xlo[32]; int xhi[32]; int xid[NR]; };
constexpr Meta make_meta() {
    Meta m{};
    m.nxi = 0;
    for (int r = 0; r < NR; ++r) {
        int lo = BOXES.b[r].x1, hi = BOXES.b[r].x2, id = -1;
        for (int i = 0; i < m.nxi; ++i) if (m.xlo[i] == lo && m.xhi[i] == hi) { id = i; break; }
        if (id < 0) { id = m.nxi; m.xlo[id] = lo; m.xhi[id] = hi; m.nxi++; }
        m.xid[r] = id;
    }
    return m;
}
constexpr Meta MT = make_meta();
constexpr int NXI = MT.nxi;
static_assert(NXI == 14, "expected 14 distinct x-intervals");

// per-h box lists (boxes whose [y1,y2) contains h) -- register y-fold
struct HRows { int cnt[Hh]; int idx[Hh][40]; };
constexpr HRows make_hb() {
    HRows hb{};
    for (int h = 0; h < Hh; ++h) {
        hb.cnt[h] = 0;
        for (int r = 0; r < NR; ++r)
            if (BOXES.b[r].y1 <= h && h < BOXES.b[r].y2) {
                hb.idx[h][hb.cnt[h]] = r;
                hb.cnt[h]++;
            }
    }
    return hb;
}
constexpr HRows HB = make_hb();
constexpr int hb_max() { int m = 0; for (int h = 0; h < Hh; ++h) m = HB.cnt[h] > m ? HB.cnt[h] : m; return m; }
static_assert(hb_max() <= 40, "HB idx array too small");

__device__ __forceinline__ ushort f2bf(float f) {  // RNE float->bf16 (finite; -inf ok)
    union { float f; unsigned u; } v; v.f = f;
    unsigned r = v.u + 0x7FFFu + ((v.u >> 16) & 1u);
    return (ushort)(r >> 16);
}
__device__ __forceinline__ float bf2f(ushort u) {
    union { unsigned u; float f; } v; v.u = ((unsigned)u) << 16;
    return v.f;
}

// swizzled index into m_s[72][512]: 16B slots XOR'd by row&7 (matches GEMM read)
__device__ __forceinline__ int midx(int r, int c) {
    return r * Cc + (((c >> 3) ^ (r & 7)) << 3) + (c & 7);
}

// ---------------- kernel 0: W fp32 -> bf16 ----------------
__global__ __launch_bounds__(256) void k_convw(const float* __restrict__ w,
                                               ushort* __restrict__ o) {
    int i = (blockIdx.x * 256 + threadIdx.x) * 4;
    float4 f = *(const float4*)&w[i];
    ushort4 u;
    u.x = f2bf(f.x); u.y = f2bf(f.y); u.z = f2bf(f.z); u.w = f2bf(f.w);
    *(ushort4*)&o[i] = u;
}

// ---------------- fused: REGISTER pooling (thread = channel) -> GEMM -------------
// vs round 6: (a) LDS cut to ~74 KB (MROWS=72) so TWO independent blocks fit per
// CU -- decoupled phase overlap (one pools while the other GEMMs); (b) pooling
// uses live-range retirement (acc born at y1, written to m_s at y2-1, ~36 live
// regs instead of 70) + explicit row double-buffer so row h+1's loads hide under
// row h's fold. GEMM + epilogue identical to the verified round-0 code.
__global__ __launch_bounds__(512) void k_fused(const float* __restrict__ x,
                                               const ushort* __restrict__ wbf,
                                               const float* __restrict__ bias,
                                               float* __restrict__ out) {
    __shared__ __align__(16) ushort m_s[MROWS * Cc];         // 72 KB, XOR-swizzled
    __shared__ float ss_s[PadR];

    struct EScratch {                                        // 4.96 KB, aliases m_s
        float rowss[PadR][8];
        float rns[PadR];
        float y_s[Cc];
        float red2[8];
    };
    EScratch* sc = (EScratch*)m_s;

    const int b = blockIdx.x;
    const int tid = threadIdx.x;
    const int lane = tid & 63;
    const int wv = tid >> 6;                // 0..7
    const int l15 = lane & 15, lhi = lane >> 4;

    // zero rows 70,71 (2 rows x 512 ushort = 512 uints) and ss_s tail
    {
        uint* z = (uint*)&m_s[70 * Cc];
        z[tid] = 0;
        if (tid >= 70 && tid < PadR) ss_s[tid] = 0.f;
    }

    // ---- register pooling: live-range retirement + row double-buffer ----
    float acc70[NR];                         // allocator keeps only live ranges
    const float* xc = x + (size_t)b * (Hh * Ww * Cc) + tid;  // channel = tid

    float rowbuf[2][Ww];
    #pragma unroll
    for (int w = 0; w < Ww; ++w) rowbuf[0][w] = xc[w * Cc];

    #pragma unroll
    for (int h = 0; h < Hh; ++h) {
        // prefetch next row while folding this one (static parity index)
        if (h + 1 < Hh) {
            #pragma unroll
            for (int w = 0; w < Ww; ++w)
                rowbuf[(h + 1) & 1][w] = xc[((h + 1) * Ww + w) * Cc];
        }
        float rmx[NXI];
        #pragma unroll
        for (int xi = 0; xi < NXI; ++xi) {
            float mm = rowbuf[h & 1][MT.xlo[xi]];
            #pragma unroll
            for (int w = MT.xlo[xi] + 1; w < MT.xhi[xi]; ++w)
                mm = fmaxf(mm, rowbuf[h & 1][w]);
            rmx[xi] = mm;
        }
        #pragma unroll
        for (int bi = 0; bi < HB.cnt[h]; ++bi) {
            const int r = HB.idx[h][bi];                     // compile-time
            const float v = rmx[MT.xid[r]];
            acc70[r] = (BOXES.b[r].y1 == h) ? v : fmaxf(acc70[r], v);  // birth/update
            if (BOXES.b[r].y2 == h + 1)                      // retire: quantize once
                m_s[midx(r, tid)] = f2bf(acc70[r]);
        }
    }
    __syncthreads();                         // m_s complete (incl. zero rows)

    // ---- SS from m_s (same read/accumulate order as previous rounds) ----
    #pragma unroll
    for (int i = 0; i < 9; ++i) {
        const int rr = wv * 9 + i;
        if (rr < NR) {
            float s = 0.f;
            #pragma unroll
            for (int cg = 0; cg < 4; ++cg) {
                ushort2 t2 = *(const ushort2*)&m_s[midx(rr, cg * 128 + 2 * lane)];
                float m0 = bf2f(t2.x), m1 = bf2f(t2.y);
                s += m0 * m0 + m1 * m1;
            }
            s += __shfl_xor(s, 1);  s += __shfl_xor(s, 2);  s += __shfl_xor(s, 4);
            s += __shfl_xor(s, 8);  s += __shfl_xor(s, 16); s += __shfl_xor(s, 32);
            if (lane == 0) ss_s[rr] = s;
        }
    }
    __syncthreads();                         // ss_s ready

    // ---- GEMM: t[80][512] = m * W^T, A resident in m_s, no barriers ----
    f32x4 acc[5][4];
    #pragma unroll
    for (int mi = 0; mi < 5; ++mi)
        #pragma unroll
        for (int ni = 0; ni < 4; ++ni) acc[mi][ni] = (f32x4){0.f, 0.f, 0.f, 0.f};

    auto loadB = [&](bf16x8 (&bf)[4][2], int k0) {
        #pragma unroll
        for (int ni = 0; ni < 4; ++ni)
            #pragma unroll
            for (int kh = 0; kh < 2; ++kh)
                bf[ni][kh] = *(const bf16x8*)(wbf + (size_t)(wv * 64 + ni * 16 + l15) * Cc
                                              + k0 + kh * 32 + lhi * 8);
    };

    bf16x8 bfc[4][2], bfn[4][2];
    loadB(bfc, 0);
    #pragma unroll
    for (int ks = 0; ks < 8; ++ks) {
        if (ks < 7) loadB(bfn, (ks + 1) * 64);
        #pragma unroll
        for (int kh = 0; kh < 2; ++kh) {
            bf16x8 af[5];
            #pragma unroll
            for (int mi = 0; mi < 5; ++mi) {
                int row_ = mi * 16 + l15;
                // rows 72..79 don't exist in LDS: remap to zero rows 70/71
                int rc = (mi < 4) ? row_
                                  : ((row_ < MROWS) ? row_ : (70 | (row_ & 1)));
                int slot = (ks * 8 + kh * 4 + lhi) ^ (rc & 7);
                af[mi] = *(const bf16x8*)&m_s[rc * Cc + slot * 8];
            }
            #pragma unroll
            for (int mi = 0; mi < 5; ++mi)
                #pragma unroll
                for (int ni = 0; ni < 4; ++ni)
                    acc[mi][ni] = __builtin_amdgcn_mfma_f32_16x16x32_bf16(
                        af[mi], bfc[ni][kh], acc[mi][ni], 0, 0, 0);
        }
        #pragma unroll
        for (int ni = 0; ni < 4; ++ni)
            #pragma unroll
            for (int kh = 0; kh < 2; ++kh) bfc[ni][kh] = bfn[ni][kh];
    }
    __syncthreads();                          // m_s reads done; epilogue may alias

    // ---- fused epilogue: deferred A-norm + bias, row-norm, sum, final norm ----
    float bia[4];
    #pragma unroll
    for (int ni = 0; ni < 4; ++ni) bia[ni] = bias[wv * 64 + ni * 16 + l15];
    float rm[5][4];
    #pragma unroll
    for (int mi = 0; mi < 5; ++mi)
        #pragma unroll
        for (int j = 0; j < 4; ++j)
            rm[mi][j] = 1.f / fmaxf(sqrtf(ss_s[mi * 16 + lhi * 4 + j]), 1e-12f);
    #pragma unroll
    for (int mi = 0; mi < 5; ++mi)
        #pragma unroll
        for (int ni = 0; ni < 4; ++ni)
            #pragma unroll
            for (int j = 0; j < 4; ++j)
                acc[mi][ni][j] = fmaf(acc[mi][ni][j], rm[mi][j], bia[ni]);

    #pragma unroll
    for (int mi = 0; mi < 5; ++mi)
        #pragma unroll
        for (int j = 0; j < 4; ++j) {
            float s = 0.f;
            #pragma unroll
            for (int ni = 0; ni < 4; ++ni) s += acc[mi][ni][j] * acc[mi][ni][j];
            s += __shfl_xor(s, 1); s += __shfl_xor(s, 2);
            s += __shfl_xor(s, 4); s += __shfl_xor(s, 8);
            if (l15 == 0) sc->rowss[mi * 16 + lhi * 4 + j][wv] = s;
        }
    __syncthreads();
    if (tid < PadR) {
        float s = 0.f;
        #pragma unroll
        for (int w8 = 0; w8 < 8; ++w8) s += sc->rowss[tid][w8];
        sc->rns[tid] = 1.f / fmaxf(sqrtf(s), 1e-12f);
    }
    __syncthreads();

    float ys[4] = {0.f, 0.f, 0.f, 0.f};
    #pragma unroll
    for (int mi = 0; mi < 5; ++mi)
        #pragma unroll
        for (int j = 0; j < 4; ++j) {
            int row_ = mi * 16 + lhi * 4 + j;
            float w = (row_ < NR) ? sc->rns[row_] : 0.f;   // skip pad rows
            #pragma unroll
            for (int ni = 0; ni < 4; ++ni) ys[ni] = fmaf(acc[mi][ni][j], w, ys[ni]);
        }
    #pragma unroll
    for (int ni = 0; ni < 4; ++ni) {
        ys[ni] += __shfl_xor(ys[ni], 16);
        ys[ni] += __shfl_xor(ys[ni], 32);
    }
    if (lane < 16)
        #pragma unroll
        for (int ni = 0; ni < 4; ++ni) sc->y_s[wv * 64 + ni * 16 + lane] = ys[ni];
    __syncthreads();

    float yv = sc->y_s[tid];
    float s2 = yv * yv;
    s2 += __shfl_xor(s2, 1);  s2 += __shfl_xor(s2, 2);  s2 += __shfl_xor(s2, 4);
    s2 += __shfl_xor(s2, 8);  s2 += __shfl_xor(s2, 16); s2 += __shfl_xor(s2, 32);
    if (lane == 0) sc->red2[wv] = s2;
    __syncthreads();
    float tot = 0.f;
    #pragma unroll
    for (int w8 = 0; w8 < 8; ++w8) tot += sc->red2[w8];
    out[(size_t)b * Cc + tid] = yv / fmaxf(sqrtf(tot), 1e-12f);
}

// ---------------- launch ----------------
extern "C" void kernel_launch(void* const* d_in, const int* in_sizes, int n_in,
                              void* d_out, int out_size, void* d_ws, size_t ws_size,
                              hipStream_t stream) {
    const float* x  = (const float*)d_in[0];
    const float* pw = (const float*)d_in[1];
    const float* pb = (const float*)d_in[2];
    float* out = (float*)d_out;

    ushort* wbf = (ushort*)d_ws;                          // 512x512 bf16 = 0.5 MB

    k_convw<<<dim3(256), dim3(256), 0, stream>>>(pw, wbf);
    k_fused<<<dim3(Bb), dim3(512), 0, stream>>>(x, wbf, pb, out);
}